// Round 10
// baseline (166.708 us; speedup 1.0000x reference)
//
#include <hip/hip_runtime.h>
#include <hip/hip_fp16.h>

// ClassicalGCN: 2-layer GCN, N=40000, E=640000, 128 -> 128(relu) -> 64, f32.
// Round 22: replicated atomic counters. r21 established: poison fill 44.5us
// (untouchable) + Sum(kernels) ~111us {bkt_cvt ~45, agg_g12 ~40, agg2 ~18,
// scale ~4}. Bucket time is invariant to block count (640 vs 2560) with
// VALU 4% / HBM 18% -> bound by SAME-ADDRESS atomic RMW serialization
// (~16 RMWs per deg[d] through per-XCD L2). Fix:
//  - dcnt[node][r], r=chunk&3: 4 replica counters + 4x32-entry sub-bins
//    (rbin[node][r][p], 256B/node) -> per-address RMW count / 4.
//  - deg = sum of 4 (one int4 load) wherever dinv is needed.
//  - agg kernels iterate 4 sub-bin segments (pad to 8, masked self-loads).
//  - bucket/cvt/WT, scale, fused gemms, agg2 structure: r21-verified.
// Workspace ~25.7MB (<=36.1MB verified in r18). Memset now zeroes dcnt.

#define N_NODES 40000
#define DIN 128
#define DH 128
#define DOUT 64
#define NEDGES 640000
#define CAPR 32            // per-replica bin capacity (deg<=~40 total -> safe)
#define NBUCKET 2560       // 8 XCD groups x 320 chunks (r15/r19 verified)
#define I4_PER_CHUNK 500   // 160000 int4 / 320 chunks
#define NODES_PER_XCD 5000
#define NCVT 1250          // x->fp16 convert blocks
#define NWT 8              // WT1/WT2 transpose blocks

typedef _Float16 f16x8 __attribute__((ext_vector_type(8)));
typedef float f32x4 __attribute__((ext_vector_type(4)));

// ---- blocks [0,NBUCKET): bucket; [NBUCKET,+NCVT): x->fp16; last NWT: WT ----
__global__ __launch_bounds__(256) void k_bkt_cvt(
    const float* __restrict__ x, _Float16* __restrict__ xh,
    const int4* __restrict__ src4, const int4* __restrict__ dst4,
    int* __restrict__ dcnt, unsigned short* __restrict__ rbin,
    const float* __restrict__ W1, const float* __restrict__ W2,
    _Float16* __restrict__ WT1, _Float16* __restrict__ WT2)
{
    if (blockIdx.x < NBUCKET) {
        // ---- bucket: this block only handles dst in its XCD's node range ----
        const int xg = blockIdx.x & 7;            // presumed XCD id (heuristic)
        const int c  = blockIdx.x >> 3;           // edge chunk 0..319
        const int rep = c & 3;                    // counter/bin replica
        const int lo = xg * NODES_PER_XCD, hi = lo + NODES_PER_XCD;
        const int e0 = c * I4_PER_CHUNK, e1 = e0 + I4_PER_CHUNK;
        for (int e = e0 + threadIdx.x; e < e1; e += 256) {
            int4 d = dst4[e];
            int4 s = src4[e];
            if (d.x >= lo && d.x < hi) {
                int p = atomicAdd(&dcnt[d.x * 4 + rep], 1);
                if (p < CAPR) rbin[(size_t)d.x * 128 + rep * CAPR + p] = (unsigned short)s.x;
            }
            if (d.y >= lo && d.y < hi) {
                int p = atomicAdd(&dcnt[d.y * 4 + rep], 1);
                if (p < CAPR) rbin[(size_t)d.y * 128 + rep * CAPR + p] = (unsigned short)s.y;
            }
            if (d.z >= lo && d.z < hi) {
                int p = atomicAdd(&dcnt[d.z * 4 + rep], 1);
                if (p < CAPR) rbin[(size_t)d.z * 128 + rep * CAPR + p] = (unsigned short)s.z;
            }
            if (d.w >= lo && d.w < hi) {
                int p = atomicAdd(&dcnt[d.w * 4 + rep], 1);
                if (p < CAPR) rbin[(size_t)d.w * 128 + rep * CAPR + p] = (unsigned short)s.w;
            }
        }
    } else if (blockIdx.x < NBUCKET + NCVT) {
        // ---- convert: 16 f32 per thread, coalesced float4 -> f16x8 ----
        const size_t base = ((size_t)(blockIdx.x - NBUCKET) * 256 + threadIdx.x) * 16;
        float4 a0 = *(const float4*)(x + base);
        float4 a1 = *(const float4*)(x + base + 4);
        float4 a2 = *(const float4*)(x + base + 8);
        float4 a3 = *(const float4*)(x + base + 12);
        f16x8 o0 = { (_Float16)a0.x, (_Float16)a0.y, (_Float16)a0.z, (_Float16)a0.w,
                     (_Float16)a1.x, (_Float16)a1.y, (_Float16)a1.z, (_Float16)a1.w };
        f16x8 o1 = { (_Float16)a2.x, (_Float16)a2.y, (_Float16)a2.z, (_Float16)a2.w,
                     (_Float16)a3.x, (_Float16)a3.y, (_Float16)a3.z, (_Float16)a3.w };
        *(f16x8*)(xh + base)     = o0;
        *(f16x8*)(xh + base + 8) = o1;
    } else {
        // ---- WT transposes: WT1[n][k]=fp16(W1[k][n]), WT2[n][k]=fp16(W2[k][n])
        const int b = blockIdx.x - NBUCKET - NCVT;   // 0..7
        for (int i = b * 256 + threadIdx.x; i < DIN * DH; i += NWT * 256) {
            int k = i >> 7, nn = i & 127;
            WT1[nn * DIN + k] = (_Float16)W1[i];
        }
        for (int i = b * 256 + threadIdx.x; i < DH * DOUT; i += NWT * 256) {
            int k = i >> 6, nn = i & 63;
            WT2[nn * DH + k] = (_Float16)W2[i];
        }
    }
}

// ---- scale: xh[row][:] *= rsqrt(deg[row]+1), in place (8 halfs/thread) ----
__global__ __launch_bounds__(256) void k_scale(
    _Float16* __restrict__ xh, const int* __restrict__ dcnt)
{
    int idx = blockIdx.x * 256 + threadIdx.x;     // one per 8 halfs
    int row = idx >> 4;                           // 16 threads per 128-col row
    int4 dc = *(const int4*)(dcnt + row * 4);
    float dn = rsqrtf((float)(dc.x + dc.y + dc.z + dc.w + 1));
    f16x8 v = *(f16x8*)(xh + (size_t)idx * 8);
    f16x8 o;
#pragma unroll
    for (int j = 0; j < 8; ++j) o[j] = (_Float16)((float)v[j] * dn);
    *(f16x8*)(xh + (size_t)idx * 8) = o;
}

// ---- agg1 (pure sum over 4 sub-bins, 8 streams) + gemm1(+b1,relu) + gemm2.
// Block = 16 nodes = 4 waves x 4 groups(16 lanes); group owns one node;
// lane gl covers halfs [gl*8, gl*8+8) of the 128-col row.
__global__ __launch_bounds__(256) void k_agg_g12(
    const int* __restrict__ dcnt, const unsigned short* __restrict__ rbin,
    const _Float16* __restrict__ xh, const float* __restrict__ b1,
    const _Float16* __restrict__ WT1, const _Float16* __restrict__ WT2,
    _Float16* __restrict__ h2)
{
    __shared__ _Float16 ys[16][136];   // aggregated input tile (+8 pad)
    __shared__ _Float16 zs[16][136];   // post-relu hidden tile (+8 pad)
    const int w = threadIdx.x >> 6;    // wave 0..3
    const int lane = threadIdx.x & 63;
    const int g  = lane >> 4;          // group 0..3 -> node
    const int gl = lane & 15;          // lane in group -> col chunk
    const int node0 = blockIdx.x * 16;
    const int node = node0 + w * 4 + g;

    const int4 dc = *(const int4*)(dcnt + node * 4);
    const int dg = dc.x + dc.y + dc.z + dc.w;
    const float dn = rsqrtf((float)(dg + 1));

    float ac[8];
    {
        f16x8 self = *(const f16x8*)(xh + (size_t)node * DIN + gl * 8);
#pragma unroll
        for (int j = 0; j < 8; ++j) ac[j] = (float)self[j];  // xsc[d] (pre-scaled)
    }
    const unsigned short* bin = rbin + (size_t)node * 128;
#pragma unroll
    for (int r = 0; r < 4; ++r) {
        int cr = (r & 1) ? ((r & 2) ? dc.w : dc.y) : ((r & 2) ? dc.z : dc.x);
        cr = min(cr, CAPR);
        // wave-max so all lanes loop together; pads masked to 0
        int mc = cr;
        mc = max(mc, __shfl_xor(mc, 16));
        mc = max(mc, __shfl_xor(mc, 32));
        const unsigned short* sb = bin + r * CAPR;
        for (int e = 0; e < mc; e += 8) {
            uint4 pk = *(const uint4*)(sb + e);   // group-uniform, 8 indices
            int s0 = (int)(pk.x & 0xFFFF), s1 = (int)(pk.x >> 16);
            int s2 = (int)(pk.y & 0xFFFF), s3 = (int)(pk.y >> 16);
            int s4 = (int)(pk.z & 0xFFFF), s5 = (int)(pk.z >> 16);
            int s6 = (int)(pk.w & 0xFFFF), s7 = (int)(pk.w >> 16);
            float m0 = (e + 0 < cr) ? 1.f : 0.f;  s0 = (e + 0 < cr) ? s0 : node;
            float m1 = (e + 1 < cr) ? 1.f : 0.f;  s1 = (e + 1 < cr) ? s1 : node;
            float m2 = (e + 2 < cr) ? 1.f : 0.f;  s2 = (e + 2 < cr) ? s2 : node;
            float m3 = (e + 3 < cr) ? 1.f : 0.f;  s3 = (e + 3 < cr) ? s3 : node;
            float m4 = (e + 4 < cr) ? 1.f : 0.f;  s4 = (e + 4 < cr) ? s4 : node;
            float m5 = (e + 5 < cr) ? 1.f : 0.f;  s5 = (e + 5 < cr) ? s5 : node;
            float m6 = (e + 6 < cr) ? 1.f : 0.f;  s6 = (e + 6 < cr) ? s6 : node;
            float m7 = (e + 7 < cr) ? 1.f : 0.f;  s7 = (e + 7 < cr) ? s7 : node;
            f16x8 r0 = *(const f16x8*)(xh + (size_t)s0 * DIN + gl * 8);
            f16x8 r1 = *(const f16x8*)(xh + (size_t)s1 * DIN + gl * 8);
            f16x8 r2 = *(const f16x8*)(xh + (size_t)s2 * DIN + gl * 8);
            f16x8 r3 = *(const f16x8*)(xh + (size_t)s3 * DIN + gl * 8);
            f16x8 r4 = *(const f16x8*)(xh + (size_t)s4 * DIN + gl * 8);
            f16x8 r5 = *(const f16x8*)(xh + (size_t)s5 * DIN + gl * 8);
            f16x8 r6 = *(const f16x8*)(xh + (size_t)s6 * DIN + gl * 8);
            f16x8 r7 = *(const f16x8*)(xh + (size_t)s7 * DIN + gl * 8);
#pragma unroll
            for (int j = 0; j < 8; ++j) {
                ac[j] += (m0 * (float)r0[j] + m1 * (float)r1[j])
                       + (m2 * (float)r2[j] + m3 * (float)r3[j]);
                ac[j] += (m4 * (float)r4[j] + m5 * (float)r5[j])
                       + (m6 * (float)r6[j] + m7 * (float)r7[j]);
            }
        }
    }
    // ys row = dn * ac  (bias after gemm1)
    {
        f16x8 o;
#pragma unroll
        for (int j = 0; j < 8; ++j) o[j] = (_Float16)(dn * ac[j]);
        *(f16x8*)&ys[w * 4 + g][gl * 8] = o;
    }
    __syncthreads();

    const int m = lane & 15, quad = lane >> 4;
#pragma unroll
    for (int t = 0; t < 2; ++t) {
        // ---- gemm1: wave w covers hidden cols (2w+t)*16 .. +15 ----
        const int nt = w * 2 + t;
        f32x4 acc1 = (f32x4){0.f, 0.f, 0.f, 0.f};
#pragma unroll
        for (int ks = 0; ks < 4; ++ks) {
            f16x8 a = *(const f16x8*)&ys[m][ks * 32 + quad * 8];
            f16x8 b = *(const f16x8*)(WT1 + (size_t)(nt * 16 + m) * DIN + ks * 32 + quad * 8);
            acc1 = __builtin_amdgcn_mfma_f32_16x16x32_f16(a, b, acc1, 0, 0, 0);
        }
        float bias = b1[nt * 16 + m];
#pragma unroll
        for (int r = 0; r < 4; ++r) {
            float v = acc1[r] + bias;
            zs[quad * 4 + r][nt * 16 + m] = (_Float16)(v > 0.f ? v : 0.f);
        }
    }
    __syncthreads();

    {
        // ---- gemm2: wave w covers out cols w*16 .. +15; h2 pre-scaled ----
        f32x4 acc2 = (f32x4){0.f, 0.f, 0.f, 0.f};
#pragma unroll
        for (int ks = 0; ks < 4; ++ks) {
            f16x8 a = *(const f16x8*)&zs[m][ks * 32 + quad * 8];
            f16x8 b = *(const f16x8*)(WT2 + (size_t)(w * 16 + m) * DH + ks * 32 + quad * 8);
            acc2 = __builtin_amdgcn_mfma_f32_16x16x32_f16(a, b, acc2, 0, 0, 0);
        }
#pragma unroll
        for (int r = 0; r < 4; ++r) {
            int nrow = node0 + quad * 4 + r;
            int4 dc2 = *(const int4*)(dcnt + nrow * 4);
            float dnr = rsqrtf((float)(dc2.x + dc2.y + dc2.z + dc2.w + 1));
            h2[(size_t)nrow * DOUT + w * 16 + m] = (_Float16)(acc2[r] * dnr);
        }
    }
}

// ---- agg2: 8 groups/wave x 8 streams over pre-scaled h2 (64 cols/row). ----
// Block = 32 nodes = 4 waves x 8 groups(8 lanes); 4 sub-bin segments.
__global__ __launch_bounds__(256) void k_agg2(
    const int* __restrict__ dcnt, const unsigned short* __restrict__ rbin,
    const _Float16* __restrict__ h2, const float* __restrict__ b2,
    float* __restrict__ out)
{
    const int w = threadIdx.x >> 6;
    const int lane = threadIdx.x & 63;
    const int g  = lane >> 3;          // group 0..7 -> node
    const int gl = lane & 7;           // col chunk (8 halfs)
    const int node = blockIdx.x * 32 + w * 8 + g;

    const int4 dc = *(const int4*)(dcnt + node * 4);
    const int dg = dc.x + dc.y + dc.z + dc.w;
    const float dn = rsqrtf((float)(dg + 1));

    float ac[8];
    {
        f16x8 self = *(const f16x8*)(h2 + (size_t)node * DOUT + gl * 8);
#pragma unroll
        for (int j = 0; j < 8; ++j) ac[j] = (float)self[j];   // self (pre-scaled)
    }
    const unsigned short* bin = rbin + (size_t)node * 128;
#pragma unroll
    for (int r = 0; r < 4; ++r) {
        int cr = (r & 1) ? ((r & 2) ? dc.w : dc.y) : ((r & 2) ? dc.z : dc.x);
        cr = min(cr, CAPR);
        int mc = cr;
        mc = max(mc, __shfl_xor(mc, 8));
        mc = max(mc, __shfl_xor(mc, 16));
        mc = max(mc, __shfl_xor(mc, 32));
        const unsigned short* sb = bin + r * CAPR;
        for (int e = 0; e < mc; e += 8) {
            uint4 pk = *(const uint4*)(sb + e);   // group-uniform, 8 indices
            int s0 = (int)(pk.x & 0xFFFF), s1 = (int)(pk.x >> 16);
            int s2 = (int)(pk.y & 0xFFFF), s3 = (int)(pk.y >> 16);
            int s4 = (int)(pk.z & 0xFFFF), s5 = (int)(pk.z >> 16);
            int s6 = (int)(pk.w & 0xFFFF), s7 = (int)(pk.w >> 16);
            float m0 = (e + 0 < cr) ? 1.f : 0.f;  s0 = (e + 0 < cr) ? s0 : node;
            float m1 = (e + 1 < cr) ? 1.f : 0.f;  s1 = (e + 1 < cr) ? s1 : node;
            float m2 = (e + 2 < cr) ? 1.f : 0.f;  s2 = (e + 2 < cr) ? s2 : node;
            float m3 = (e + 3 < cr) ? 1.f : 0.f;  s3 = (e + 3 < cr) ? s3 : node;
            float m4 = (e + 4 < cr) ? 1.f : 0.f;  s4 = (e + 4 < cr) ? s4 : node;
            float m5 = (e + 5 < cr) ? 1.f : 0.f;  s5 = (e + 5 < cr) ? s5 : node;
            float m6 = (e + 6 < cr) ? 1.f : 0.f;  s6 = (e + 6 < cr) ? s6 : node;
            float m7 = (e + 7 < cr) ? 1.f : 0.f;  s7 = (e + 7 < cr) ? s7 : node;
            f16x8 r0 = *(const f16x8*)(h2 + (size_t)s0 * DOUT + gl * 8);
            f16x8 r1 = *(const f16x8*)(h2 + (size_t)s1 * DOUT + gl * 8);
            f16x8 r2 = *(const f16x8*)(h2 + (size_t)s2 * DOUT + gl * 8);
            f16x8 r3 = *(const f16x8*)(h2 + (size_t)s3 * DOUT + gl * 8);
            f16x8 r4 = *(const f16x8*)(h2 + (size_t)s4 * DOUT + gl * 8);
            f16x8 r5 = *(const f16x8*)(h2 + (size_t)s5 * DOUT + gl * 8);
            f16x8 r6 = *(const f16x8*)(h2 + (size_t)s6 * DOUT + gl * 8);
            f16x8 r7 = *(const f16x8*)(h2 + (size_t)s7 * DOUT + gl * 8);
#pragma unroll
            for (int j = 0; j < 8; ++j) {
                ac[j] += (m0 * (float)r0[j] + m1 * (float)r1[j])
                       + (m2 * (float)r2[j] + m3 * (float)r3[j]);
                ac[j] += (m4 * (float)r4[j] + m5 * (float)r5[j])
                       + (m6 * (float)r6[j] + m7 * (float)r7[j]);
            }
        }
    }
    // out = dn*ac + b2
    float4 ba = *(const float4*)(b2 + gl * 8);
    float4 bb = *(const float4*)(b2 + gl * 8 + 4);
    float4 o0 = { dn * ac[0] + ba.x, dn * ac[1] + ba.y,
                  dn * ac[2] + ba.z, dn * ac[3] + ba.w };
    float4 o1 = { dn * ac[4] + bb.x, dn * ac[5] + bb.y,
                  dn * ac[6] + bb.z, dn * ac[7] + bb.w };
    float* orow = out + (size_t)node * DOUT + gl * 8;
    *(float4*)orow = o0;
    *(float4*)(orow + 4) = o1;
}

extern "C" void kernel_launch(void* const* d_in, const int* in_sizes, int n_in,
                              void* d_out, int out_size, void* d_ws, size_t ws_size,
                              hipStream_t stream) {
    const float* x  = (const float*)d_in[0];
    const int*   ei = (const int*)d_in[1];   // [2, E] int32
    const float* W1 = (const float*)d_in[2];
    const float* b1 = (const float*)d_in[3];
    const float* W2 = (const float*)d_in[4];
    const float* b2 = (const float*)d_in[5];
    float* out = (float*)d_out;

    const int n = N_NODES, E = NEDGES;
    const int* src = ei;
    const int* dst = ei + E;

    // Workspace layout (bytes), ~25.7 MB (<=36.1MB verified), 16B-aligned:
    char* ws = (char*)d_ws;
    int*            dcnt = (int*)(ws + 0);                  // 640000 (4 reps)
    _Float16*       WT1  = (_Float16*)(ws + 655360);        // 32768  fp16 W1^T
    _Float16*       WT2  = (_Float16*)(ws + 688128);        // 16384  fp16 W2^T
    unsigned short* rbin = (unsigned short*)(ws + 704512);  // 10.24MB 4x32 bins
    _Float16*       xh   = (_Float16*)(ws + 11190272);      // 10.24MB fp16 x
    _Float16*       h2   = (_Float16*)(ws + 21676032);      // 5.12MB fp16 (scaled)

    hipMemsetAsync(dcnt, 0, N_NODES * 4 * sizeof(int), stream);
    k_bkt_cvt <<<NBUCKET + NCVT + NWT, 256, 0, stream>>>(x, xh, (const int4*)src,
                                                         (const int4*)dst, dcnt, rbin,
                                                         W1, W2, WT1, WT2);
    k_scale   <<<(N_NODES * DIN / 8) / 256, 256, 0, stream>>>(xh, dcnt);
    k_agg_g12 <<<n / 16, 256, 0, stream>>>(dcnt, rbin, xh, b1, WT1, WT2, h2);
    k_agg2    <<<n / 32, 256, 0, stream>>>(dcnt, rbin, h2, b2, out);
}

// Round 11
// 164.053 us; speedup vs baseline: 1.0162x; 1.0162x over previous
//
#include <hip/hip_runtime.h>
#include <hip/hip_fp16.h>

// ClassicalGCN: 2-layer GCN, N=40000, E=640000, 128 -> 128(relu) -> 64, f32.
// Round 23: r21 base (verified best, 158.8us) + ONE change: gather unroll
// 8 -> 16 (two uint4 bin loads/iter, 16 masked row-streams in flight per
// group). r22's counter replication regressed (agg +7us) -> reverted.
// Rationale: poison fill flushes L3 each iter; agg_g12 FETCH ~65MB of 164MB
// logical -> ~40% of gathers pay ~900cy HBM miss -> latency-bound; the only
// lever that has worked (r20->r21: unroll 4->8, -7.5us) is in-flight misses
// per wave. VGPR ~32->~90 trades occupancy 8->5-6 waves/SIMD for 2x MLP.
// Workspace ~20.7MB, r12-verified offsets. Numerics identical to r21.

#define N_NODES 40000
#define DIN 128
#define DH 128
#define DOUT 64
#define NEDGES 640000
#define CAP 64             // bin capacity; realized max degree ~35
#define NBUCKET 2560       // 8 XCD groups x 320 chunks (r15/r19 verified)
#define I4_PER_CHUNK 500   // 160000 int4 / 320 chunks
#define NODES_PER_XCD 5000
#define NCVT 1250          // x->fp16 convert blocks
#define NWT 8              // WT1/WT2 transpose blocks

typedef _Float16 f16x8 __attribute__((ext_vector_type(8)));
typedef float f32x4 __attribute__((ext_vector_type(4)));

// ---- blocks [0,NBUCKET): bucket; [NBUCKET,+NCVT): x->fp16; last NWT: WT ----
__global__ __launch_bounds__(256) void k_bkt_cvt(
    const float* __restrict__ x, _Float16* __restrict__ xh,
    const int4* __restrict__ src4, const int4* __restrict__ dst4,
    int* __restrict__ deg, unsigned short* __restrict__ ssrc,
    const float* __restrict__ W1, const float* __restrict__ W2,
    _Float16* __restrict__ WT1, _Float16* __restrict__ WT2)
{
    if (blockIdx.x < NBUCKET) {
        // ---- bucket: this block only handles dst in its XCD's node range ----
        const int xg = blockIdx.x & 7;            // presumed XCD id (heuristic)
        const int c  = blockIdx.x >> 3;           // edge chunk 0..319
        const int lo = xg * NODES_PER_XCD, hi = lo + NODES_PER_XCD;
        const int e0 = c * I4_PER_CHUNK, e1 = e0 + I4_PER_CHUNK;
        for (int e = e0 + threadIdx.x; e < e1; e += 256) {
            int4 d = dst4[e];
            int4 s = src4[e];
            if (d.x >= lo && d.x < hi) {
                int p = atomicAdd(&deg[d.x], 1);
                if (p < CAP) ssrc[d.x * CAP + p] = (unsigned short)s.x;
            }
            if (d.y >= lo && d.y < hi) {
                int p = atomicAdd(&deg[d.y], 1);
                if (p < CAP) ssrc[d.y * CAP + p] = (unsigned short)s.y;
            }
            if (d.z >= lo && d.z < hi) {
                int p = atomicAdd(&deg[d.z], 1);
                if (p < CAP) ssrc[d.z * CAP + p] = (unsigned short)s.z;
            }
            if (d.w >= lo && d.w < hi) {
                int p = atomicAdd(&deg[d.w], 1);
                if (p < CAP) ssrc[d.w * CAP + p] = (unsigned short)s.w;
            }
        }
    } else if (blockIdx.x < NBUCKET + NCVT) {
        // ---- convert: 16 f32 per thread, coalesced float4 -> f16x8 ----
        const size_t base = ((size_t)(blockIdx.x - NBUCKET) * 256 + threadIdx.x) * 16;
        float4 a0 = *(const float4*)(x + base);
        float4 a1 = *(const float4*)(x + base + 4);
        float4 a2 = *(const float4*)(x + base + 8);
        float4 a3 = *(const float4*)(x + base + 12);
        f16x8 o0 = { (_Float16)a0.x, (_Float16)a0.y, (_Float16)a0.z, (_Float16)a0.w,
                     (_Float16)a1.x, (_Float16)a1.y, (_Float16)a1.z, (_Float16)a1.w };
        f16x8 o1 = { (_Float16)a2.x, (_Float16)a2.y, (_Float16)a2.z, (_Float16)a2.w,
                     (_Float16)a3.x, (_Float16)a3.y, (_Float16)a3.z, (_Float16)a3.w };
        *(f16x8*)(xh + base)     = o0;
        *(f16x8*)(xh + base + 8) = o1;
    } else {
        // ---- WT transposes: WT1[n][k]=fp16(W1[k][n]), WT2[n][k]=fp16(W2[k][n])
        const int b = blockIdx.x - NBUCKET - NCVT;   // 0..7
        for (int i = b * 256 + threadIdx.x; i < DIN * DH; i += NWT * 256) {
            int k = i >> 7, nn = i & 127;
            WT1[nn * DIN + k] = (_Float16)W1[i];
        }
        for (int i = b * 256 + threadIdx.x; i < DH * DOUT; i += NWT * 256) {
            int k = i >> 6, nn = i & 63;
            WT2[nn * DH + k] = (_Float16)W2[i];
        }
    }
}

// ---- scale: xh[row][:] *= rsqrt(deg[row]+1), in place (8 halfs/thread) ----
__global__ __launch_bounds__(256) void k_scale(
    _Float16* __restrict__ xh, const int* __restrict__ deg)
{
    int idx = blockIdx.x * 256 + threadIdx.x;     // one per 8 halfs
    int row = idx >> 4;                           // 16 threads per 128-col row
    float dn = rsqrtf((float)(deg[row] + 1));
    f16x8 v = *(f16x8*)(xh + (size_t)idx * 8);
    f16x8 o;
#pragma unroll
    for (int j = 0; j < 8; ++j) o[j] = (_Float16)((float)v[j] * dn);
    *(f16x8*)(xh + (size_t)idx * 8) = o;
}

// ---- agg1 (16 streams/group, pure sum) + gemm1(+b1,relu) + gemm2(*dinv).
// Block = 16 nodes = 4 waves x 4 groups(16 lanes); group owns one node;
// lane gl covers halfs [gl*8, gl*8+8) of the 128-col row.
__global__ __launch_bounds__(256) void k_agg_g12(
    const int* __restrict__ deg, const unsigned short* __restrict__ ssrc,
    const _Float16* __restrict__ xh, const float* __restrict__ b1,
    const _Float16* __restrict__ WT1, const _Float16* __restrict__ WT2,
    _Float16* __restrict__ h2)
{
    __shared__ _Float16 ys[16][136];   // aggregated input tile (+8 pad)
    __shared__ _Float16 zs[16][136];   // post-relu hidden tile (+8 pad)
    const int w = threadIdx.x >> 6;    // wave 0..3
    const int lane = threadIdx.x & 63;
    const int g  = lane >> 4;          // group 0..3 -> node
    const int gl = lane & 15;          // lane in group -> col chunk
    const int node0 = blockIdx.x * 16;
    const int node = node0 + w * 4 + g;

    const int dg = deg[node];
    const int cnt = min(dg, CAP);
    const float dn = rsqrtf((float)(dg + 1));

    float ac[8];
    {
        f16x8 self = *(const f16x8*)(xh + (size_t)node * DIN + gl * 8);
#pragma unroll
        for (int j = 0; j < 8; ++j) ac[j] = (float)self[j];  // xsc[d] (pre-scaled)
    }
    // wave-max cnt so all lanes loop together; pads masked to 0
    int mc = cnt;
    mc = max(mc, __shfl_xor(mc, 16));
    mc = max(mc, __shfl_xor(mc, 32));

    const unsigned short* bin = ssrc + (size_t)node * CAP;
    for (int e = 0; e < mc; e += 16) {
        uint4 pa = *(const uint4*)(bin + e);      // group-uniform, 8 indices
        uint4 pb = *(const uint4*)(bin + e + 8);  // next 8 (CAP=64 -> in-bounds)
        int s0 = (int)(pa.x & 0xFFFF), s1 = (int)(pa.x >> 16);
        int s2 = (int)(pa.y & 0xFFFF), s3 = (int)(pa.y >> 16);
        int s4 = (int)(pa.z & 0xFFFF), s5 = (int)(pa.z >> 16);
        int s6 = (int)(pa.w & 0xFFFF), s7 = (int)(pa.w >> 16);
        int s8 = (int)(pb.x & 0xFFFF), s9 = (int)(pb.x >> 16);
        int sA = (int)(pb.y & 0xFFFF), sB = (int)(pb.y >> 16);
        int sC = (int)(pb.z & 0xFFFF), sD = (int)(pb.z >> 16);
        int sE = (int)(pb.w & 0xFFFF), sF = (int)(pb.w >> 16);
        float m0 = (e + 0 < cnt) ? 1.f : 0.f;  s0 = (e + 0 < cnt) ? s0 : node;
        float m1 = (e + 1 < cnt) ? 1.f : 0.f;  s1 = (e + 1 < cnt) ? s1 : node;
        float m2 = (e + 2 < cnt) ? 1.f : 0.f;  s2 = (e + 2 < cnt) ? s2 : node;
        float m3 = (e + 3 < cnt) ? 1.f : 0.f;  s3 = (e + 3 < cnt) ? s3 : node;
        float m4 = (e + 4 < cnt) ? 1.f : 0.f;  s4 = (e + 4 < cnt) ? s4 : node;
        float m5 = (e + 5 < cnt) ? 1.f : 0.f;  s5 = (e + 5 < cnt) ? s5 : node;
        float m6 = (e + 6 < cnt) ? 1.f : 0.f;  s6 = (e + 6 < cnt) ? s6 : node;
        float m7 = (e + 7 < cnt) ? 1.f : 0.f;  s7 = (e + 7 < cnt) ? s7 : node;
        float m8 = (e + 8 < cnt) ? 1.f : 0.f;  s8 = (e + 8 < cnt) ? s8 : node;
        float m9 = (e + 9 < cnt) ? 1.f : 0.f;  s9 = (e + 9 < cnt) ? s9 : node;
        float mA = (e + 10 < cnt) ? 1.f : 0.f; sA = (e + 10 < cnt) ? sA : node;
        float mB = (e + 11 < cnt) ? 1.f : 0.f; sB = (e + 11 < cnt) ? sB : node;
        float mC = (e + 12 < cnt) ? 1.f : 0.f; sC = (e + 12 < cnt) ? sC : node;
        float mD = (e + 13 < cnt) ? 1.f : 0.f; sD = (e + 13 < cnt) ? sD : node;
        float mE = (e + 14 < cnt) ? 1.f : 0.f; sE = (e + 14 < cnt) ? sE : node;
        float mF = (e + 15 < cnt) ? 1.f : 0.f; sF = (e + 15 < cnt) ? sF : node;
        f16x8 r0 = *(const f16x8*)(xh + (size_t)s0 * DIN + gl * 8);
        f16x8 r1 = *(const f16x8*)(xh + (size_t)s1 * DIN + gl * 8);
        f16x8 r2 = *(const f16x8*)(xh + (size_t)s2 * DIN + gl * 8);
        f16x8 r3 = *(const f16x8*)(xh + (size_t)s3 * DIN + gl * 8);
        f16x8 r4 = *(const f16x8*)(xh + (size_t)s4 * DIN + gl * 8);
        f16x8 r5 = *(const f16x8*)(xh + (size_t)s5 * DIN + gl * 8);
        f16x8 r6 = *(const f16x8*)(xh + (size_t)s6 * DIN + gl * 8);
        f16x8 r7 = *(const f16x8*)(xh + (size_t)s7 * DIN + gl * 8);
        f16x8 r8 = *(const f16x8*)(xh + (size_t)s8 * DIN + gl * 8);
        f16x8 r9 = *(const f16x8*)(xh + (size_t)s9 * DIN + gl * 8);
        f16x8 rA = *(const f16x8*)(xh + (size_t)sA * DIN + gl * 8);
        f16x8 rB = *(const f16x8*)(xh + (size_t)sB * DIN + gl * 8);
        f16x8 rC = *(const f16x8*)(xh + (size_t)sC * DIN + gl * 8);
        f16x8 rD = *(const f16x8*)(xh + (size_t)sD * DIN + gl * 8);
        f16x8 rE = *(const f16x8*)(xh + (size_t)sE * DIN + gl * 8);
        f16x8 rF = *(const f16x8*)(xh + (size_t)sF * DIN + gl * 8);
#pragma unroll
        for (int j = 0; j < 8; ++j) {
            float t0 = (m0 * (float)r0[j] + m1 * (float)r1[j])
                     + (m2 * (float)r2[j] + m3 * (float)r3[j]);
            float t1 = (m4 * (float)r4[j] + m5 * (float)r5[j])
                     + (m6 * (float)r6[j] + m7 * (float)r7[j]);
            float t2 = (m8 * (float)r8[j] + m9 * (float)r9[j])
                     + (mA * (float)rA[j] + mB * (float)rB[j]);
            float t3 = (mC * (float)rC[j] + mD * (float)rD[j])
                     + (mE * (float)rE[j] + mF * (float)rF[j]);
            ac[j] += (t0 + t1) + (t2 + t3);
        }
    }
    // ys row = dn * ac  (bias after gemm1)
    {
        f16x8 o;
#pragma unroll
        for (int j = 0; j < 8; ++j) o[j] = (_Float16)(dn * ac[j]);
        *(f16x8*)&ys[w * 4 + g][gl * 8] = o;
    }
    __syncthreads();

    const int m = lane & 15, quad = lane >> 4;
#pragma unroll
    for (int t = 0; t < 2; ++t) {
        // ---- gemm1: wave w covers hidden cols (2w+t)*16 .. +15 ----
        const int nt = w * 2 + t;
        f32x4 acc1 = (f32x4){0.f, 0.f, 0.f, 0.f};
#pragma unroll
        for (int ks = 0; ks < 4; ++ks) {
            f16x8 a = *(const f16x8*)&ys[m][ks * 32 + quad * 8];
            f16x8 b = *(const f16x8*)(WT1 + (size_t)(nt * 16 + m) * DIN + ks * 32 + quad * 8);
            acc1 = __builtin_amdgcn_mfma_f32_16x16x32_f16(a, b, acc1, 0, 0, 0);
        }
        float bias = b1[nt * 16 + m];
#pragma unroll
        for (int r = 0; r < 4; ++r) {
            float v = acc1[r] + bias;
            zs[quad * 4 + r][nt * 16 + m] = (_Float16)(v > 0.f ? v : 0.f);
        }
    }
    __syncthreads();

    {
        // ---- gemm2: wave w covers out cols w*16 .. +15; h2 pre-scaled ----
        f32x4 acc2 = (f32x4){0.f, 0.f, 0.f, 0.f};
#pragma unroll
        for (int ks = 0; ks < 4; ++ks) {
            f16x8 a = *(const f16x8*)&zs[m][ks * 32 + quad * 8];
            f16x8 b = *(const f16x8*)(WT2 + (size_t)(w * 16 + m) * DH + ks * 32 + quad * 8);
            acc2 = __builtin_amdgcn_mfma_f32_16x16x32_f16(a, b, acc2, 0, 0, 0);
        }
#pragma unroll
        for (int r = 0; r < 4; ++r) {
            int nrow = node0 + quad * 4 + r;
            float dnr = rsqrtf((float)(deg[nrow] + 1));
            h2[(size_t)nrow * DOUT + w * 16 + m] = (_Float16)(acc2[r] * dnr);
        }
    }
}

// ---- agg2: 8 groups/wave x 16 streams over pre-scaled h2 (64 cols/row).
// Block = 32 nodes = 4 waves x 8 groups(8 lanes).
__global__ __launch_bounds__(256) void k_agg2(
    const int* __restrict__ deg, const unsigned short* __restrict__ ssrc,
    const _Float16* __restrict__ h2, const float* __restrict__ b2,
    float* __restrict__ out)
{
    const int w = threadIdx.x >> 6;
    const int lane = threadIdx.x & 63;
    const int g  = lane >> 3;          // group 0..7 -> node
    const int gl = lane & 7;           // col chunk (8 halfs)
    const int node = blockIdx.x * 32 + w * 8 + g;

    const int dg = deg[node];
    const int cnt = min(dg, CAP);
    const float dn = rsqrtf((float)(dg + 1));

    float ac[8];
    {
        f16x8 self = *(const f16x8*)(h2 + (size_t)node * DOUT + gl * 8);
#pragma unroll
        for (int j = 0; j < 8; ++j) ac[j] = (float)self[j];   // self (pre-scaled)
    }
    int mc = cnt;
    mc = max(mc, __shfl_xor(mc, 8));
    mc = max(mc, __shfl_xor(mc, 16));
    mc = max(mc, __shfl_xor(mc, 32));

    const unsigned short* bin = ssrc + (size_t)node * CAP;
    for (int e = 0; e < mc; e += 16) {
        uint4 pa = *(const uint4*)(bin + e);      // group-uniform, 8 indices
        uint4 pb = *(const uint4*)(bin + e + 8);  // next 8 (CAP=64 -> in-bounds)
        int s0 = (int)(pa.x & 0xFFFF), s1 = (int)(pa.x >> 16);
        int s2 = (int)(pa.y & 0xFFFF), s3 = (int)(pa.y >> 16);
        int s4 = (int)(pa.z & 0xFFFF), s5 = (int)(pa.z >> 16);
        int s6 = (int)(pa.w & 0xFFFF), s7 = (int)(pa.w >> 16);
        int s8 = (int)(pb.x & 0xFFFF), s9 = (int)(pb.x >> 16);
        int sA = (int)(pb.y & 0xFFFF), sB = (int)(pb.y >> 16);
        int sC = (int)(pb.z & 0xFFFF), sD = (int)(pb.z >> 16);
        int sE = (int)(pb.w & 0xFFFF), sF = (int)(pb.w >> 16);
        float m0 = (e + 0 < cnt) ? 1.f : 0.f;  s0 = (e + 0 < cnt) ? s0 : node;
        float m1 = (e + 1 < cnt) ? 1.f : 0.f;  s1 = (e + 1 < cnt) ? s1 : node;
        float m2 = (e + 2 < cnt) ? 1.f : 0.f;  s2 = (e + 2 < cnt) ? s2 : node;
        float m3 = (e + 3 < cnt) ? 1.f : 0.f;  s3 = (e + 3 < cnt) ? s3 : node;
        float m4 = (e + 4 < cnt) ? 1.f : 0.f;  s4 = (e + 4 < cnt) ? s4 : node;
        float m5 = (e + 5 < cnt) ? 1.f : 0.f;  s5 = (e + 5 < cnt) ? s5 : node;
        float m6 = (e + 6 < cnt) ? 1.f : 0.f;  s6 = (e + 6 < cnt) ? s6 : node;
        float m7 = (e + 7 < cnt) ? 1.f : 0.f;  s7 = (e + 7 < cnt) ? s7 : node;
        float m8 = (e + 8 < cnt) ? 1.f : 0.f;  s8 = (e + 8 < cnt) ? s8 : node;
        float m9 = (e + 9 < cnt) ? 1.f : 0.f;  s9 = (e + 9 < cnt) ? s9 : node;
        float mA = (e + 10 < cnt) ? 1.f : 0.f; sA = (e + 10 < cnt) ? sA : node;
        float mB = (e + 11 < cnt) ? 1.f : 0.f; sB = (e + 11 < cnt) ? sB : node;
        float mC = (e + 12 < cnt) ? 1.f : 0.f; sC = (e + 12 < cnt) ? sC : node;
        float mD = (e + 13 < cnt) ? 1.f : 0.f; sD = (e + 13 < cnt) ? sD : node;
        float mE = (e + 14 < cnt) ? 1.f : 0.f; sE = (e + 14 < cnt) ? sE : node;
        float mF = (e + 15 < cnt) ? 1.f : 0.f; sF = (e + 15 < cnt) ? sF : node;
        f16x8 r0 = *(const f16x8*)(h2 + (size_t)s0 * DOUT + gl * 8);
        f16x8 r1 = *(const f16x8*)(h2 + (size_t)s1 * DOUT + gl * 8);
        f16x8 r2 = *(const f16x8*)(h2 + (size_t)s2 * DOUT + gl * 8);
        f16x8 r3 = *(const f16x8*)(h2 + (size_t)s3 * DOUT + gl * 8);
        f16x8 r4 = *(const f16x8*)(h2 + (size_t)s4 * DOUT + gl * 8);
        f16x8 r5 = *(const f16x8*)(h2 + (size_t)s5 * DOUT + gl * 8);
        f16x8 r6 = *(const f16x8*)(h2 + (size_t)s6 * DOUT + gl * 8);
        f16x8 r7 = *(const f16x8*)(h2 + (size_t)s7 * DOUT + gl * 8);
        f16x8 r8 = *(const f16x8*)(h2 + (size_t)s8 * DOUT + gl * 8);
        f16x8 r9 = *(const f16x8*)(h2 + (size_t)s9 * DOUT + gl * 8);
        f16x8 rA = *(const f16x8*)(h2 + (size_t)sA * DOUT + gl * 8);
        f16x8 rB = *(const f16x8*)(h2 + (size_t)sB * DOUT + gl * 8);
        f16x8 rC = *(const f16x8*)(h2 + (size_t)sC * DOUT + gl * 8);
        f16x8 rD = *(const f16x8*)(h2 + (size_t)sD * DOUT + gl * 8);
        f16x8 rE = *(const f16x8*)(h2 + (size_t)sE * DOUT + gl * 8);
        f16x8 rF = *(const f16x8*)(h2 + (size_t)sF * DOUT + gl * 8);
#pragma unroll
        for (int j = 0; j < 8; ++j) {
            float t0 = (m0 * (float)r0[j] + m1 * (float)r1[j])
                     + (m2 * (float)r2[j] + m3 * (float)r3[j]);
            float t1 = (m4 * (float)r4[j] + m5 * (float)r5[j])
                     + (m6 * (float)r6[j] + m7 * (float)r7[j]);
            float t2 = (m8 * (float)r8[j] + m9 * (float)r9[j])
                     + (mA * (float)rA[j] + mB * (float)rB[j]);
            float t3 = (mC * (float)rC[j] + mD * (float)rD[j])
                     + (mE * (float)rE[j] + mF * (float)rF[j]);
            ac[j] += (t0 + t1) + (t2 + t3);
        }
    }
    // out = dn*ac + b2
    float4 ba = *(const float4*)(b2 + gl * 8);
    float4 bb = *(const float4*)(b2 + gl * 8 + 4);
    float4 o0 = { dn * ac[0] + ba.x, dn * ac[1] + ba.y,
                  dn * ac[2] + ba.z, dn * ac[3] + ba.w };
    float4 o1 = { dn * ac[4] + bb.x, dn * ac[5] + bb.y,
                  dn * ac[6] + bb.z, dn * ac[7] + bb.w };
    float* orow = out + (size_t)node * DOUT + gl * 8;
    *(float4*)orow = o0;
    *(float4*)(orow + 4) = o1;
}

extern "C" void kernel_launch(void* const* d_in, const int* in_sizes, int n_in,
                              void* d_out, int out_size, void* d_ws, size_t ws_size,
                              hipStream_t stream) {
    const float* x  = (const float*)d_in[0];
    const int*   ei = (const int*)d_in[1];   // [2, E] int32
    const float* W1 = (const float*)d_in[2];
    const float* b1 = (const float*)d_in[3];
    const float* W2 = (const float*)d_in[4];
    const float* b2 = (const float*)d_in[5];
    float* out = (float*)d_out;

    const int n = N_NODES, E = NEDGES;
    const int* src = ei;
    const int* dst = ei + E;

    // Workspace layout (bytes), ~20.7 MB (byte-identical to verified r12):
    char* ws = (char*)d_ws;
    int*            deg  = (int*)(ws + 0);                 // 160000
    _Float16*       WT1  = (_Float16*)(ws + 163840);       // 32768  fp16 W1^T
    _Float16*       WT2  = (_Float16*)(ws + 196608);       // 16384  fp16 W2^T
    unsigned short* ssrc = (unsigned short*)(ws + 212992); // 5.12MB ushort bins
    _Float16*       xh   = (_Float16*)(ws + 5332992);      // 10.24MB fp16 x
    _Float16*       h2   = (_Float16*)(ws + 15572992);     // 5.12MB fp16 (scaled)

    hipMemsetAsync(deg, 0, N_NODES * sizeof(int), stream);
    k_bkt_cvt <<<NBUCKET + NCVT + NWT, 256, 0, stream>>>(x, xh, (const int4*)src,
                                                         (const int4*)dst, deg, ssrc,
                                                         W1, W2, WT1, WT2);
    k_scale   <<<(N_NODES * DIN / 8) / 256, 256, 0, stream>>>(xh, deg);
    k_agg_g12 <<<n / 16, 256, 0, stream>>>(deg, ssrc, xh, b1, WT1, WT2, h2);
    k_agg2    <<<n / 32, 256, 0, stream>>>(deg, ssrc, h2, b2, out);
}

// Round 12
// 156.634 us; speedup vs baseline: 1.0643x; 1.0474x over previous
//
#include <hip/hip_runtime.h>
#include <hip/hip_fp16.h>

// ClassicalGCN: 2-layer GCN, N=40000, E=640000, 128 -> 128(relu) -> 64, f32.
// Round 24: gemm-first order restored (r12-verified: full gemm1 hides under
// the bucket's atomic bubbles, bucket||gemm1 = 44.7us = bucket alone), with
// r21's verified group-gather for the agg kernels. r23's unroll-16 regressed
// (stream depth saturates at 8) -> unroll-8 kept.
//   k_init  : deg=0 + WT1/WT2 fp16 transposes (r12-verified)
//   k_work1 : bucket(640 blks, r12 cfg) || gemm1 x*W1 -> h1 fp16 unscaled
//   k_scale : h1 *= dinv[row] in place (r16-verified numerics)
//   k_agg_g2: group-gather h1sc (pure sum, unroll 8) -> z=relu(dn*acc+b1)
//             -> zs tile -> gemm2 -> h2 = (z W2)*dinv (pre-scaled)
//   k_agg2  : r21-verified (8-lane groups, 16 streams... unroll 8)
// Workspace ~20.7MB, r12-verified offsets. absmax path == r16 (passed 2e-3).

#define N_NODES 40000
#define DIN 128
#define DH 128
#define DOUT 64
#define NEDGES 640000
#define CAP 64             // bin capacity; realized max degree ~35
#define NBUCKET 640        // 8 XCD groups x 80 chunks (r12 verified config)
#define I4_PER_CHUNK 2000  // 160000 int4 / 80 chunks
#define NODES_PER_XCD 5000

typedef _Float16 f16x8 __attribute__((ext_vector_type(8)));
typedef float f32x4 __attribute__((ext_vector_type(4)));

// ---- init: zero deg + build WT1[n][k]=fp16(W1[k][n]), WT2[n][k]=fp16(W2[k][n])
__global__ void k_init(int* __restrict__ deg, const float* __restrict__ W1,
                       const float* __restrict__ W2,
                       _Float16* __restrict__ WT1, _Float16* __restrict__ WT2, int n) {
    int i = blockIdx.x * 256 + threadIdx.x;
    if (i < n) deg[i] = 0;
    if (i < DIN * DH) {
        int k = i >> 7, nn = i & 127;            // W1 row-major [k][n], n=128
        WT1[(size_t)nn * DIN + k] = (_Float16)W1[i];
    }
    if (i < DH * DOUT) {
        int k = i >> 6, nn = i & 63;             // W2 row-major [k][n], n=64
        WT2[(size_t)nn * DH + k] = (_Float16)W2[i];
    }
}

// ---- work1: blocks [0,640) = XCD-local bucket; [640,1265) = gemm1 MFMA ----
__global__ __launch_bounds__(256) void k_work1(
    const float* __restrict__ x, const _Float16* __restrict__ WT,
    __half* __restrict__ h,
    const int4* __restrict__ src4, const int4* __restrict__ dst4,
    int* __restrict__ deg, unsigned short* __restrict__ ssrc)
{
    if (blockIdx.x < NBUCKET) {
        // ---- bucket: this block only handles dst in its XCD's node range ----
        const int xg = blockIdx.x & 7;            // presumed XCD id (heuristic)
        const int c  = blockIdx.x >> 3;           // edge chunk 0..79
        const int lo = xg * NODES_PER_XCD, hi = lo + NODES_PER_XCD;
        const int e0 = c * I4_PER_CHUNK, e1 = e0 + I4_PER_CHUNK;
        for (int e = e0 + threadIdx.x; e < e1; e += 256) {
            int4 d = dst4[e];
            int4 s = src4[e];
            if (d.x >= lo && d.x < hi) {
                int p = atomicAdd(&deg[d.x], 1);
                if (p < CAP) ssrc[d.x * CAP + p] = (unsigned short)s.x;
            }
            if (d.y >= lo && d.y < hi) {
                int p = atomicAdd(&deg[d.y], 1);
                if (p < CAP) ssrc[d.y * CAP + p] = (unsigned short)s.y;
            }
            if (d.z >= lo && d.z < hi) {
                int p = atomicAdd(&deg[d.z], 1);
                if (p < CAP) ssrc[d.z * CAP + p] = (unsigned short)s.z;
            }
            if (d.w >= lo && d.w < hi) {
                int p = atomicAdd(&deg[d.w], 1);
                if (p < CAP) ssrc[d.w * CAP + p] = (unsigned short)s.w;
            }
        }
    } else {
        // ---- gemm1: one wave = 16 rows x 128 cols, K=128, UNSCALED out ----
        const int wave = (blockIdx.x - NBUCKET) * 4 + (threadIdx.x >> 6);  // 0..2499
        const int lane = threadIdx.x & 63;
        const int m = lane & 15, quad = lane >> 4;

        f32x4 acc[8];
#pragma unroll
        for (int nt = 0; nt < 8; ++nt) acc[nt] = (f32x4){0.f, 0.f, 0.f, 0.f};

        const float* xrow = x + (size_t)(wave * 16 + m) * DIN + quad * 8;
#pragma unroll
        for (int ks = 0; ks < 4; ++ks) {
            float4 xa = *(const float4*)(xrow + ks * 32);
            float4 xb = *(const float4*)(xrow + ks * 32 + 4);
            f16x8 a = { (_Float16)xa.x, (_Float16)xa.y, (_Float16)xa.z, (_Float16)xa.w,
                        (_Float16)xb.x, (_Float16)xb.y, (_Float16)xb.z, (_Float16)xb.w };
#pragma unroll
            for (int nt = 0; nt < 8; ++nt) {
                f16x8 b = *(const f16x8*)(WT + (size_t)(nt * 16 + m) * DIN + ks * 32 + quad * 8);
                acc[nt] = __builtin_amdgcn_mfma_f32_16x16x32_f16(a, b, acc[nt], 0, 0, 0);
            }
        }
#pragma unroll
        for (int r = 0; r < 4; ++r) {
            int orow = wave * 16 + quad * 4 + r;
#pragma unroll
            for (int nt = 0; nt < 8; ++nt)
                h[(size_t)orow * DH + nt * 16 + m] = (__half)acc[nt][r];
        }
    }
}

// ---- scale: h1[row][:] *= rsqrt(deg[row]+1), in place (8 halfs/thread) ----
__global__ __launch_bounds__(256) void k_scale(
    _Float16* __restrict__ h1, const int* __restrict__ deg)
{
    int idx = blockIdx.x * 256 + threadIdx.x;     // one per 8 halfs
    int row = idx >> 4;                           // 16 threads per 128-col row
    float dn = rsqrtf((float)(deg[row] + 1));
    f16x8 v = *(f16x8*)(h1 + (size_t)idx * 8);
    f16x8 o;
#pragma unroll
    for (int j = 0; j < 8; ++j) o[j] = (_Float16)((float)v[j] * dn);
    *(f16x8*)(h1 + (size_t)idx * 8) = o;
}

// ---- agg1 (8 streams/group, pure sum over pre-scaled h1) + bias/relu
// -> zs tile -> gemm2(*dinv) -> h2. Block = 16 nodes = 4 waves x 4 groups.
__global__ __launch_bounds__(256) void k_agg_g2(
    const int* __restrict__ deg, const unsigned short* __restrict__ ssrc,
    const _Float16* __restrict__ h1, const float* __restrict__ b1,
    const _Float16* __restrict__ WT2, _Float16* __restrict__ h2)
{
    __shared__ _Float16 zs[16][136];   // post-relu hidden tile (+8 pad)
    const int w = threadIdx.x >> 6;    // wave 0..3
    const int lane = threadIdx.x & 63;
    const int g  = lane >> 4;          // group 0..3 -> node
    const int gl = lane & 15;          // lane in group -> col chunk (8 halfs)
    const int node0 = blockIdx.x * 16;
    const int node = node0 + w * 4 + g;

    const int dg = deg[node];
    const int cnt = min(dg, CAP);
    const float dn = rsqrtf((float)(dg + 1));

    float ac[8];
    {
        f16x8 self = *(const f16x8*)(h1 + (size_t)node * DIN + gl * 8);
#pragma unroll
        for (int j = 0; j < 8; ++j) ac[j] = (float)self[j];  // h1sc[d] (pre-scaled)
    }
    // wave-max cnt so all lanes loop together; pads masked to 0
    int mc = cnt;
    mc = max(mc, __shfl_xor(mc, 16));
    mc = max(mc, __shfl_xor(mc, 32));

    const unsigned short* bin = ssrc + (size_t)node * CAP;
    for (int e = 0; e < mc; e += 8) {
        uint4 pk = *(const uint4*)(bin + e);      // group-uniform, 8 indices
        int s0 = (int)(pk.x & 0xFFFF), s1 = (int)(pk.x >> 16);
        int s2 = (int)(pk.y & 0xFFFF), s3 = (int)(pk.y >> 16);
        int s4 = (int)(pk.z & 0xFFFF), s5 = (int)(pk.z >> 16);
        int s6 = (int)(pk.w & 0xFFFF), s7 = (int)(pk.w >> 16);
        float m0 = (e + 0 < cnt) ? 1.f : 0.f;  s0 = (e + 0 < cnt) ? s0 : node;
        float m1 = (e + 1 < cnt) ? 1.f : 0.f;  s1 = (e + 1 < cnt) ? s1 : node;
        float m2 = (e + 2 < cnt) ? 1.f : 0.f;  s2 = (e + 2 < cnt) ? s2 : node;
        float m3 = (e + 3 < cnt) ? 1.f : 0.f;  s3 = (e + 3 < cnt) ? s3 : node;
        float m4 = (e + 4 < cnt) ? 1.f : 0.f;  s4 = (e + 4 < cnt) ? s4 : node;
        float m5 = (e + 5 < cnt) ? 1.f : 0.f;  s5 = (e + 5 < cnt) ? s5 : node;
        float m6 = (e + 6 < cnt) ? 1.f : 0.f;  s6 = (e + 6 < cnt) ? s6 : node;
        float m7 = (e + 7 < cnt) ? 1.f : 0.f;  s7 = (e + 7 < cnt) ? s7 : node;
        f16x8 r0 = *(const f16x8*)(h1 + (size_t)s0 * DIN + gl * 8);
        f16x8 r1 = *(const f16x8*)(h1 + (size_t)s1 * DIN + gl * 8);
        f16x8 r2 = *(const f16x8*)(h1 + (size_t)s2 * DIN + gl * 8);
        f16x8 r3 = *(const f16x8*)(h1 + (size_t)s3 * DIN + gl * 8);
        f16x8 r4 = *(const f16x8*)(h1 + (size_t)s4 * DIN + gl * 8);
        f16x8 r5 = *(const f16x8*)(h1 + (size_t)s5 * DIN + gl * 8);
        f16x8 r6 = *(const f16x8*)(h1 + (size_t)s6 * DIN + gl * 8);
        f16x8 r7 = *(const f16x8*)(h1 + (size_t)s7 * DIN + gl * 8);
#pragma unroll
        for (int j = 0; j < 8; ++j) {
            ac[j] += (m0 * (float)r0[j] + m1 * (float)r1[j])
                   + (m2 * (float)r2[j] + m3 * (float)r3[j]);
            ac[j] += (m4 * (float)r4[j] + m5 * (float)r5[j])
                   + (m6 * (float)r6[j] + m7 * (float)r7[j]);
        }
    }
    // z = relu(dn * ac + b1), straight into the gemm2 A-tile
    {
        float4 ba = *(const float4*)(b1 + gl * 8);
        float4 bb = *(const float4*)(b1 + gl * 8 + 4);
        f16x8 o;
        float v0 = dn * ac[0] + ba.x; o[0] = (_Float16)(v0 > 0.f ? v0 : 0.f);
        float v1 = dn * ac[1] + ba.y; o[1] = (_Float16)(v1 > 0.f ? v1 : 0.f);
        float v2 = dn * ac[2] + ba.z; o[2] = (_Float16)(v2 > 0.f ? v2 : 0.f);
        float v3 = dn * ac[3] + ba.w; o[3] = (_Float16)(v3 > 0.f ? v3 : 0.f);
        float v4 = dn * ac[4] + bb.x; o[4] = (_Float16)(v4 > 0.f ? v4 : 0.f);
        float v5 = dn * ac[5] + bb.y; o[5] = (_Float16)(v5 > 0.f ? v5 : 0.f);
        float v6 = dn * ac[6] + bb.z; o[6] = (_Float16)(v6 > 0.f ? v6 : 0.f);
        float v7 = dn * ac[7] + bb.w; o[7] = (_Float16)(v7 > 0.f ? v7 : 0.f);
        *(f16x8*)&zs[w * 4 + g][gl * 8] = o;
    }
    __syncthreads();

    {
        // ---- gemm2: wave w covers out cols w*16 .. +15; h2 pre-scaled ----
        const int m = lane & 15, quad = lane >> 4;
        f32x4 acc2 = (f32x4){0.f, 0.f, 0.f, 0.f};
#pragma unroll
        for (int ks = 0; ks < 4; ++ks) {
            f16x8 a = *(const f16x8*)&zs[m][ks * 32 + quad * 8];
            f16x8 b = *(const f16x8*)(WT2 + (size_t)(w * 16 + m) * DH + ks * 32 + quad * 8);
            acc2 = __builtin_amdgcn_mfma_f32_16x16x32_f16(a, b, acc2, 0, 0, 0);
        }
#pragma unroll
        for (int r = 0; r < 4; ++r) {
            int nrow = node0 + quad * 4 + r;
            float dnr = rsqrtf((float)(deg[nrow] + 1));
            h2[(size_t)nrow * DOUT + w * 16 + m] = (_Float16)(acc2[r] * dnr);
        }
    }
}

// ---- agg2: 8 groups/wave x 8 streams over pre-scaled h2 (64 cols/row).
// Block = 32 nodes = 4 waves x 8 groups(8 lanes).
__global__ __launch_bounds__(256) void k_agg2(
    const int* __restrict__ deg, const unsigned short* __restrict__ ssrc,
    const _Float16* __restrict__ h2, const float* __restrict__ b2,
    float* __restrict__ out)
{
    const int w = threadIdx.x >> 6;
    const int lane = threadIdx.x & 63;
    const int g  = lane >> 3;          // group 0..7 -> node
    const int gl = lane & 7;           // col chunk (8 halfs)
    const int node = blockIdx.x * 32 + w * 8 + g;

    const int dg = deg[node];
    const int cnt = min(dg, CAP);
    const float dn = rsqrtf((float)(dg + 1));

    float ac[8];
    {
        f16x8 self = *(const f16x8*)(h2 + (size_t)node * DOUT + gl * 8);
#pragma unroll
        for (int j = 0; j < 8; ++j) ac[j] = (float)self[j];   // self (pre-scaled)
    }
    int mc = cnt;
    mc = max(mc, __shfl_xor(mc, 8));
    mc = max(mc, __shfl_xor(mc, 16));
    mc = max(mc, __shfl_xor(mc, 32));

    const unsigned short* bin = ssrc + (size_t)node * CAP;
    for (int e = 0; e < mc; e += 8) {
        uint4 pk = *(const uint4*)(bin + e);      // group-uniform, 8 indices
        int s0 = (int)(pk.x & 0xFFFF), s1 = (int)(pk.x >> 16);
        int s2 = (int)(pk.y & 0xFFFF), s3 = (int)(pk.y >> 16);
        int s4 = (int)(pk.z & 0xFFFF), s5 = (int)(pk.z >> 16);
        int s6 = (int)(pk.w & 0xFFFF), s7 = (int)(pk.w >> 16);
        float m0 = (e + 0 < cnt) ? 1.f : 0.f;  s0 = (e + 0 < cnt) ? s0 : node;
        float m1 = (e + 1 < cnt) ? 1.f : 0.f;  s1 = (e + 1 < cnt) ? s1 : node;
        float m2 = (e + 2 < cnt) ? 1.f : 0.f;  s2 = (e + 2 < cnt) ? s2 : node;
        float m3 = (e + 3 < cnt) ? 1.f : 0.f;  s3 = (e + 3 < cnt) ? s3 : node;
        float m4 = (e + 4 < cnt) ? 1.f : 0.f;  s4 = (e + 4 < cnt) ? s4 : node;
        float m5 = (e + 5 < cnt) ? 1.f : 0.f;  s5 = (e + 5 < cnt) ? s5 : node;
        float m6 = (e + 6 < cnt) ? 1.f : 0.f;  s6 = (e + 6 < cnt) ? s6 : node;
        float m7 = (e + 7 < cnt) ? 1.f : 0.f;  s7 = (e + 7 < cnt) ? s7 : node;
        f16x8 r0 = *(const f16x8*)(h2 + (size_t)s0 * DOUT + gl * 8);
        f16x8 r1 = *(const f16x8*)(h2 + (size_t)s1 * DOUT + gl * 8);
        f16x8 r2 = *(const f16x8*)(h2 + (size_t)s2 * DOUT + gl * 8);
        f16x8 r3 = *(const f16x8*)(h2 + (size_t)s3 * DOUT + gl * 8);
        f16x8 r4 = *(const f16x8*)(h2 + (size_t)s4 * DOUT + gl * 8);
        f16x8 r5 = *(const f16x8*)(h2 + (size_t)s5 * DOUT + gl * 8);
        f16x8 r6 = *(const f16x8*)(h2 + (size_t)s6 * DOUT + gl * 8);
        f16x8 r7 = *(const f16x8*)(h2 + (size_t)s7 * DOUT + gl * 8);
#pragma unroll
        for (int j = 0; j < 8; ++j) {
            ac[j] += (m0 * (float)r0[j] + m1 * (float)r1[j])
                   + (m2 * (float)r2[j] + m3 * (float)r3[j]);
            ac[j] += (m4 * (float)r4[j] + m5 * (float)r5[j])
                   + (m6 * (float)r6[j] + m7 * (float)r7[j]);
        }
    }
    // out = dn*ac + b2
    float4 ba = *(const float4*)(b2 + gl * 8);
    float4 bb = *(const float4*)(b2 + gl * 8 + 4);
    float4 o0 = { dn * ac[0] + ba.x, dn * ac[1] + ba.y,
                  dn * ac[2] + ba.z, dn * ac[3] + ba.w };
    float4 o1 = { dn * ac[4] + bb.x, dn * ac[5] + bb.y,
                  dn * ac[6] + bb.z, dn * ac[7] + bb.w };
    float* orow = out + (size_t)node * DOUT + gl * 8;
    *(float4*)orow = o0;
    *(float4*)(orow + 4) = o1;
}

extern "C" void kernel_launch(void* const* d_in, const int* in_sizes, int n_in,
                              void* d_out, int out_size, void* d_ws, size_t ws_size,
                              hipStream_t stream) {
    const float* x  = (const float*)d_in[0];
    const int*   ei = (const int*)d_in[1];   // [2, E] int32
    const float* W1 = (const float*)d_in[2];
    const float* b1 = (const float*)d_in[3];
    const float* W2 = (const float*)d_in[4];
    const float* b2 = (const float*)d_in[5];
    float* out = (float*)d_out;

    const int n = N_NODES, E = NEDGES;
    const int* src = ei;
    const int* dst = ei + E;

    // Workspace layout (bytes), ~20.7 MB (byte-identical to verified r12):
    char* ws = (char*)d_ws;
    int*            deg  = (int*)(ws + 0);                 // 160000
    _Float16*       WT1  = (_Float16*)(ws + 163840);       // 32768  fp16 W1^T
    _Float16*       WT2  = (_Float16*)(ws + 196608);       // 16384  fp16 W2^T
    unsigned short* ssrc = (unsigned short*)(ws + 212992); // 5.12MB ushort bins
    _Float16*       h1   = (_Float16*)(ws + 5332992);      // 10.24MB fp16
    _Float16*       h2   = (_Float16*)(ws + 15572992);     // 5.12MB fp16 (scaled)

    k_init   <<<(n + 255) / 256, 256, 0, stream>>>(deg, W1, W2, WT1, WT2, n);
    k_work1  <<<NBUCKET + 625, 256, 0, stream>>>(x, WT1, (__half*)h1,
                                                 (const int4*)src, (const int4*)dst,
                                                 deg, ssrc);
    k_scale  <<<(N_NODES * DH / 8) / 256, 256, 0, stream>>>(h1, deg);
    k_agg_g2 <<<n / 16, 256, 0, stream>>>(deg, ssrc, h1, b1, WT2, h2);
    k_agg2   <<<n / 32, 256, 0, stream>>>(deg, ssrc, h2, b2, out);
}